// Round 11
// baseline (443.028 us; speedup 1.0000x reference)
//
#include <hip/hip_runtime.h>

#define HW 512
#define NPIX (HW*HW)
#define NSAMP 64
#define KSEL 2621
#define NF 3
#define NQ (NF*NSAMP)
#define CAP 16384
#define CPAD 32     // counter padding (uints) -> 128B apart, no false sharing
#define SBCAP 2048  // per-block candidate buffer (E~292/block, huge margin)

#define HALO 3
#define LSTR 520    // LDS row stride in floats (16B-aligned, bank-friendly)
#define ROWS 16
#define TR (ROWS + 2*HALO)   // 22
#define NV4 (TR*128)         // staged float4 per strip = 2816

// Analytic bracket: sim ~ N(0, ||w||^2) exactly (x iid normal). Single-sided:
// candidates = all |bits| >= T_lo; E[count] ~ 9.4K in [KSEL, CAP] with ~70
// sigma margins. Exactness never depends on it: violations poison -> full
// plane radix fallback in sel_final.
#define Z_LO 2.1

// Weight LDS offsets
#define W3OFF 0
#define W5OFF 9
#define W7OFF 34
#define WTOT 83

// ===========================================================================
// Row-streaming conv (round-5 lesson: small live set, no spills).
// ===========================================================================
template<int K, int R>
__device__ __forceinline__ void conv_rows_f64(
    const float (*xt)[LSTR], const double* __restrict__ wsm,
    int tx, double* __restrict__ acc)
{
  constexpr int ROFF = HALO - K/2;
  constexpr int COFF = 4 - K/2;
  #pragma unroll
  for (int y = 0; y < R + K - 1; ++y) {
    double v[K];
    #pragma unroll
    for (int j = 0; j < K; ++j)
      v[j] = (double)xt[y + ROFF][tx + j + COFF];
    #pragma unroll
    for (int i = 0; i < K; ++i) {
      const int r = y - i;                 // compile-time after unroll
      if (r >= 0 && r < R) {
        #pragma unroll
        for (int j = 0; j < K; ++j)
          acc[r] = fma(v[j], wsm[i*K + j], acc[r]);
      }
    }
  }
}

template<int K, int R>
__device__ __forceinline__ void conv_rows_f32(
    const float (*xt)[LSTR], const float* __restrict__ wsm,
    int tx, float* __restrict__ acc)
{
  constexpr int ROFF = HALO - K/2;
  constexpr int COFF = 4 - K/2;
  #pragma unroll
  for (int y = 0; y < R + K - 1; ++y) {
    float v[K];
    #pragma unroll
    for (int j = 0; j < K; ++j)
      v[j] = xt[y + ROFF][tx + j + COFF];
    #pragma unroll
    for (int i = 0; i < K; ++i) {
      const int r = y - i;
      if (r >= 0 && r < R) {
        #pragma unroll
        for (int j = 0; j < K; ++j)
          acc[r] = fmaf(v[j], wsm[i*K + j], acc[r]);
      }
    }
  }
}

// Descending scans of LDS hist (coarse-256 + fine).
__device__ __forceinline__ void scan2048_desc(
    const unsigned* lh, unsigned* part, int t, unsigned kr,
    unsigned* out_bin, unsigned* out_krem)
{
  unsigned sum = 0;
  #pragma unroll
  for (int i = 0; i < 8; ++i) sum += lh[t*8 + i];
  part[t] = sum;
  __syncthreads();
  if (t == 0) {
    unsigned cum = 0; int sc = 0;
    for (int c = 255; c >= 0; --c) {
      if (cum + part[c] >= kr) { sc = c; break; }
      cum += part[c];
    }
    unsigned cum2 = cum; int sb = sc*8;
    for (int b = sc*8 + 7; b >= sc*8; --b) {
      if (cum2 + lh[b] >= kr) { sb = b; break; }
      cum2 += lh[b];
    }
    *out_bin = (unsigned)sb; *out_krem = kr - cum2;
  }
  __syncthreads();
}

__device__ __forceinline__ void scan512_desc(
    const unsigned* lh, unsigned* part, int t, unsigned kr,
    unsigned* out_bin)
{
  part[t] = lh[2*t] + lh[2*t + 1];
  __syncthreads();
  if (t == 0) {
    unsigned cum = 0; int sc = 0;
    for (int c = 255; c >= 0; --c) {
      if (cum + part[c] >= kr) { sc = c; break; }
      cum += part[c];
    }
    unsigned cum2 = cum; int sb = 2*sc;
    for (int b = 2*sc + 1; b >= 2*sc; --b) {
      if (cum2 + lh[b] >= kr) { sb = b; break; }
      cum2 += lh[b];
    }
    *out_bin = (unsigned)sb;
  }
  __syncthreads();
}

// ===========================================================================
// winit: analytic bracket threshold from ||w||_2 per filter.
// ===========================================================================
__global__ void winit(const float* __restrict__ w3, const float* __restrict__ w5,
                      const float* __restrict__ w7, unsigned* __restrict__ tlo)
{
  const int t = threadIdx.x;
  if (t < 3) {
    const float* w = (t == 0) ? w3 : (t == 1) ? w5 : w7;
    const int n = (t == 0) ? 9 : (t == 1) ? 25 : 49;
    double s2 = 0.0;
    for (int i = 0; i < n; ++i) s2 = fma((double)w[i], (double)w[i], s2);
    tlo[t] = __float_as_uint((float)(Z_LO * sqrt(s2)));
  }
}

// ===========================================================================
// Forward: fp64 conv (exact selection), per-filter barriers (round-9 lesson),
// MINIMAL single-sided compaction epilogue (round-10 lesson: the two-sided
// count+shfl epilogue blew the 128-VGPR cap -> 270MB scratch writes).
// ===========================================================================
__global__ __launch_bounds__(512, 2) void fwd_all(
    const float* __restrict__ x,
    const float* __restrict__ w3, const float* __restrict__ w5,
    const float* __restrict__ w7,
    float* __restrict__ sims,
    const unsigned* __restrict__ tlo,
    unsigned* __restrict__ cntC, unsigned* __restrict__ cand)
{
  __shared__ float xt[TR][LSTR];
  __shared__ double wsm[WTOT];
  __shared__ unsigned sb[SBCAP];
  __shared__ unsigned scnt, sbase;

  const int tid = threadIdx.x;
  const int s  = blockIdx.y;
  const int by = blockIdx.x * ROWS;
  const float* __restrict__ xs = x + (size_t)s*NPIX;

  if (tid < WTOT) {
    double wv;
    if (tid < W5OFF)      wv = (double)w3[tid];
    else if (tid < W7OFF) wv = (double)w5[tid - W5OFF];
    else                  wv = (double)w7[tid - W7OFF];
    wsm[tid] = wv;
  }
  if (tid == 0) scnt = 0;
  if (tid < TR*8) {
    const int r = tid >> 3, c = tid & 7;
    xt[r][(c < 4) ? c : 512 + c] = 0.0f;
  }
  #pragma unroll 2
  for (int idx = tid; idx < NV4; idx += 512) {
    const int r = idx >> 7, c4 = idx & 127;
    const int gy = by + r - HALO;
    float4 v = make_float4(0.f, 0.f, 0.f, 0.f);
    if (gy >= 0 && gy < HW)
      v = ((const float4*)(xs + (size_t)gy*HW))[c4];
    *(float4*)&xt[r][4 + 4*c4] = v;
  }
  __syncthreads();

  const int tx = tid;
  const size_t obase = (size_t)s*NPIX + (size_t)by*HW + tx;

  #pragma unroll
  for (int f = 0; f < NF; ++f) {
    const unsigned Tl = tlo[f];
    const int q = f*NSAMP + s;

    double acc[ROWS];
    #pragma unroll
    for (int r = 0; r < ROWS; ++r) acc[r] = 0.0;
    if (f == 0)      conv_rows_f64<3, ROWS>(xt, wsm + W3OFF, tx, acc);
    else if (f == 1) conv_rows_f64<5, ROWS>(xt, wsm + W5OFF, tx, acc);
    else             conv_rows_f64<7, ROWS>(xt, wsm + W7OFF, tx, acc);

    float* __restrict__ so = sims + (size_t)f*NSAMP*NPIX + obase;
    #pragma unroll
    for (int r = 0; r < ROWS; ++r) {
      const float sv = (float)acc[r];
      so[(size_t)r*HW] = sv;
      const unsigned bits = __float_as_uint(sv) & 0x7fffffffu;
      if (bits >= Tl) {
        const unsigned pos = atomicAdd(&scnt, 1u);
        if (pos < SBCAP) sb[pos] = bits;
      }
    }
    __syncthreads();

    const unsigned nb = scnt;
    if (tid == 0) {
      sbase = nb ? atomicAdd(&cntC[(size_t)q*CPAD], nb) : 0u;
      if (nb > SBCAP) atomicAdd(&cntC[(size_t)q*CPAD], (unsigned)(CAP + 1)); // poison
    }
    __syncthreads();
    const unsigned base = sbase;
    const unsigned nstore = (nb < (unsigned)SBCAP) ? nb : (unsigned)SBCAP;
    for (unsigned i = tid; i < nstore; i += 512) {
      const unsigned pos = base + i;
      if (pos < CAP) cand[(size_t)q*CAP + pos] = sb[i];
    }
    if (f < NF - 1) {
      __syncthreads();
      if (tid == 0) scnt = 0;
      __syncthreads();
    }
  }
}

// ===========================================================================
// Exact selection: all elements >= T_lo are in cand, so the KSEL-th largest
// overall is the KSEL-th largest in cand. 3-level radix on the compact list;
// full-plane fallback if bracket invalid/overflowed.
// ===========================================================================
__global__ __launch_bounds__(256) void sel_final(
    const unsigned* __restrict__ cntC, const unsigned* __restrict__ cand,
    const float* __restrict__ sims, unsigned* __restrict__ thb)
{
  __shared__ unsigned lh[2048];
  __shared__ unsigned part[256];
  __shared__ unsigned sbin, skrem;
  const int q = blockIdx.x, t = threadIdx.x;

  const unsigned nC = cntC[(size_t)q*CPAD];
  const unsigned* __restrict__ cq = cand + (size_t)q*CAP;
  const float*    __restrict__ sq = sims + (size_t)q*NPIX;
  const bool ok = (nC >= (unsigned)KSEL) && (nC <= (unsigned)CAP);
  const unsigned kr0 = (unsigned)KSEL;

  for (int i = t; i < 2048; i += 256) lh[i] = 0;
  __syncthreads();
  if (ok) {
    for (unsigned i = t; i < nC; i += 256) atomicAdd(&lh[cq[i] >> 20], 1u);
  } else {
    for (int i = t; i < NPIX; i += 256) {
      const unsigned b = __float_as_uint(sq[i]) & 0x7fffffffu;
      atomicAdd(&lh[b >> 20], 1u);
    }
  }
  __syncthreads();
  scan2048_desc(lh, part, t, kr0, &sbin, &skrem);
  const unsigned pfx1 = sbin << 20;
  const unsigned kr1  = skrem;

  for (int i = t; i < 2048; i += 256) lh[i] = 0;
  __syncthreads();
  if (ok) {
    for (unsigned i = t; i < nC; i += 256) {
      const unsigned b = cq[i];
      if ((b >> 20) == (pfx1 >> 20)) atomicAdd(&lh[(b >> 9) & 0x7ffu], 1u);
    }
  } else {
    for (int i = t; i < NPIX; i += 256) {
      const unsigned b = __float_as_uint(sq[i]) & 0x7fffffffu;
      if ((b >> 20) == (pfx1 >> 20)) atomicAdd(&lh[(b >> 9) & 0x7ffu], 1u);
    }
  }
  __syncthreads();
  scan2048_desc(lh, part, t, kr1, &sbin, &skrem);
  const unsigned pfx2 = pfx1 | (sbin << 9);
  const unsigned kr2  = skrem;

  for (int i = t; i < 512; i += 256) lh[i] = 0;
  __syncthreads();
  if (ok) {
    for (unsigned i = t; i < nC; i += 256) {
      const unsigned b = cq[i];
      if ((b >> 9) == (pfx2 >> 9)) atomicAdd(&lh[b & 0x1ffu], 1u);
    }
  } else {
    for (int i = t; i < NPIX; i += 256) {
      const unsigned b = __float_as_uint(sq[i]) & 0x7fffffffu;
      if ((b >> 9) == (pfx2 >> 9)) atomicAdd(&lh[b & 0x1ffu], 1u);
    }
  }
  __syncthreads();
  scan512_desc(lh, part, t, kr2, &sbin);
  if (t == 0) thb[q] = pfx2 | sbin;
}

// ===========================================================================
// Backward: plain per-filter stage -> sync -> conv -> sync (round-9 lesson:
// pre[6] async-split cost 24 VGPR at the cap and was neutral). unroll 2 on
// staging so the compiler doesn't keep 6 float4 concurrently live.
// ===========================================================================
__global__ __launch_bounds__(512, 2) void bwd_all(
    const float* __restrict__ sims,
    const float* __restrict__ w3, const float* __restrict__ w5,
    const float* __restrict__ w7,
    const unsigned* __restrict__ thb, float* __restrict__ out)
{
  __shared__ float xt[TR][LSTR];
  __shared__ float wsm[WTOT];

  const int tid = threadIdx.x;
  const int s  = blockIdx.y;
  const int by = blockIdx.x * ROWS;
  const int tx = tid;

  if (tid < WTOT) {
    float wv;
    if (tid < W5OFF)      wv = w3[tid];
    else if (tid < W7OFF) wv = w5[tid - W5OFF];
    else                  wv = w7[tid - W7OFF];
    wsm[tid] = wv;
  }
  if (tid < TR*8) {
    const int r = tid >> 3, c = tid & 7;
    xt[r][(c < 4) ? c : 512 + c] = 0.0f;
  }

  float acc[ROWS];
  #pragma unroll
  for (int r = 0; r < ROWS; ++r) acc[r] = 0.0f;

  #pragma unroll
  for (int f = 0; f < NF; ++f) {
    __syncthreads();                    // pads/wsm done, prev conv done
    const unsigned th = thb[f*NSAMP + s];
    const float* __restrict__ ss = sims + ((size_t)f*NSAMP + s)*NPIX;

    #pragma unroll 2
    for (int idx = tid; idx < NV4; idx += 512) {
      const int r = idx >> 7, c4 = idx & 127;
      const int gy = by + r - HALO;
      float4 v = make_float4(0.f, 0.f, 0.f, 0.f);
      if (gy >= 0 && gy < HW) {
        v = ((const float4*)(ss + (size_t)gy*HW))[c4];
        if ((__float_as_uint(v.x) & 0x7fffffffu) < th) v.x = 0.0f;
        if ((__float_as_uint(v.y) & 0x7fffffffu) < th) v.y = 0.0f;
        if ((__float_as_uint(v.z) & 0x7fffffffu) < th) v.z = 0.0f;
        if ((__float_as_uint(v.w) & 0x7fffffffu) < th) v.w = 0.0f;
      }
      *(float4*)&xt[r][4 + 4*c4] = v;
    }
    __syncthreads();

    if (f == 0)      conv_rows_f32<3, ROWS>(xt, wsm + W3OFF, tx, acc);
    else if (f == 1) conv_rows_f32<5, ROWS>(xt, wsm + W5OFF, tx, acc);
    else             conv_rows_f32<7, ROWS>(xt, wsm + W7OFF, tx, acc);
  }

  float* __restrict__ oo = out + (size_t)s*NPIX + (size_t)by*HW + tx;
  #pragma unroll
  for (int r = 0; r < ROWS; ++r)
    oo[(size_t)r*HW] = acc[r];
}

// ===========================================================================
extern "C" void kernel_launch(void* const* d_in, const int* in_sizes, int n_in,
                              void* d_out, int out_size, void* d_ws, size_t ws_size,
                              hipStream_t stream)
{
  const float* x  = (const float*)d_in[0];
  const float* w3 = (const float*)d_in[1];
  const float* w5 = (const float*)d_in[2];
  const float* w7 = (const float*)d_in[3];
  float* out = (float*)d_out;
  char* ws = (char*)d_ws;

  const size_t SIMS_B = (size_t)NF*NSAMP*NPIX*sizeof(float);   // 192 MB
  const size_t CNT_B  = (size_t)NQ*CPAD*sizeof(unsigned);      // 24 KB

  float*    sims = (float*)ws;
  unsigned* cntC = (unsigned*)(ws + SIMS_B);
  unsigned* tlo  = cntC + (size_t)NQ*CPAD;
  unsigned* thb  = tlo + 8;
  unsigned* cand = thb + NQ + NQ;      // spare NQ gap

  hipMemsetAsync(cntC, 0, CNT_B, stream);

  winit<<<1, 64, 0, stream>>>(w3, w5, w7, tlo);
  dim3 b512(512, 1, 1);
  dim3 sg(HW/ROWS, NSAMP, 1);          // 32 x 64 strips
  fwd_all<<<sg, b512, 0, stream>>>(x, w3, w5, w7, sims, tlo, cntC, cand);
  sel_final<<<NQ, 256, 0, stream>>>(cntC, cand, sims, thb);
  bwd_all<<<sg, b512, 0, stream>>>(sims, w3, w5, w7, thb, out);
}